// Round 1
// baseline (19641.350 us; speedup 1.0000x reference)
//
#include <hip/hip_runtime.h>

// GRU: T=2048, B=64, IN=H=256, L=3, 3H=768.
// Strategy:
//   kernel 1 (convert): f32->bf16 weights/x, fold b_ih (+ b_hh for r,z) into bias.
//   kernel 2 (gemm_gx, per layer): gx = inp_bf16 @ Wih^T + bias. r,z cols -> bf16
//     buffer [T*B][512]; n cols -> f32 buffer [T*B][256] (tanh passes error at
//     slope 1, so keep xn exact).
//   kernel 3 (gru_layer, per layer): persistent, 4 WGs x 512 thr, 16 batch rows
//     per WG (batch rows are independent -> no inter-WG sync). Whh held in VGPRs
//     (192/thread), h in LDS (f32 + bf16), gx prefetched 1 step ahead via
//     global_load_lds. 2 barriers/step.

typedef float  float4_  __attribute__((ext_vector_type(4)));
typedef short  short8_  __attribute__((ext_vector_type(8)));

#define DEVFN static __device__ __forceinline__

constexpr int T_ = 2048;
constexpr int B_ = 64;
constexpr int H_ = 256;
constexpr int G_ = 768;

DEVFN unsigned short f2bf(float f) {
  unsigned u = __float_as_uint(f);
  u += 0x7fffu + ((u >> 16) & 1u);   // round-to-nearest-even
  return (unsigned short)(u >> 16);
}
DEVFN float bf2f(unsigned short s) { return __uint_as_float(((unsigned)s) << 16); }
DEVFN float rcp_(float x)  { return __builtin_amdgcn_rcpf(x); }
DEVFN float exp2_(float x) { return __builtin_amdgcn_exp2f(x); }
DEVFN float sigmoid_(float x) { return rcp_(1.f + exp2_(-1.4426950408889634f * x)); }
DEVFN float tanh_(float x)    { return 1.f - 2.f * rcp_(1.f + exp2_(2.8853900817779268f * x)); }

DEVFN void load_lds16(const void* g, void* l) {
  __builtin_amdgcn_global_load_lds(
      (__attribute__((address_space(1))) void*)g,
      (__attribute__((address_space(3))) void*)l, 16, 0, 0);
}

// ---------------------------------------------------------------- convert ----
__global__ void convert_kernel(const float* __restrict__ x,
                               const float* __restrict__ wih,
                               const float* __restrict__ whh,
                               const float* __restrict__ bih,
                               const float* __restrict__ bhh,
                               unsigned short* __restrict__ xb,
                               unsigned short* __restrict__ wihb,
                               unsigned short* __restrict__ whhb,
                               float* __restrict__ biasf,
                               float* __restrict__ bhhn) {
  const long i0 = (long)blockIdx.x * blockDim.x + threadIdx.x;
  const long stride = (long)gridDim.x * blockDim.x;
  for (long i = i0; i < (long)T_ * B_ * H_; i += stride) xb[i] = f2bf(x[i]);
  for (long i = i0; i < 3L * G_ * H_; i += stride) {
    wihb[i] = f2bf(wih[i]);
    whhb[i] = f2bf(whh[i]);
  }
  for (long i = i0; i < 3L * G_; i += stride) {
    int g = (int)(i % G_);
    biasf[i] = bih[i] + (g < 512 ? bhh[i] : 0.f);  // b_hh_n stays separate
  }
  for (long i = i0; i < 3L * H_; i += stride) {
    int l = (int)(i >> 8), j = (int)(i & 255);
    bhhn[i] = bhh[l * G_ + 512 + j];
  }
}

// ---------------------------------------------------------------- gemm_gx ----
// C[row][g] = A[row][:] . W[g][:] + bias[g];  A:[131072][256] bf16, W:[768][256] bf16
// grid = (6 col-tiles, 1024 row-tiles), 256 threads, 128x128 tile, BK=32.
__global__ __launch_bounds__(256) void gemm_gx(const unsigned short* __restrict__ A,
                                               const unsigned short* __restrict__ W,
                                               const float* __restrict__ bias,
                                               unsigned short* __restrict__ gxrz,
                                               float* __restrict__ gxn) {
  __shared__ alignas(16) unsigned short As[128 * 32];
  __shared__ alignas(16) unsigned short Bs[128 * 32];
  const int tid = threadIdx.x;
  const int bn = blockIdx.x;
  const size_t bm = blockIdx.y;
  const int wave = tid >> 6, lane = tid & 63;
  const int q = lane >> 4, nl = lane & 15;
  const int wr = (wave >> 1) * 64, wc = (wave & 1) * 64;
  const unsigned short* Ab = A + bm * 128 * 256;
  const unsigned short* Wb = W + (size_t)bn * 128 * 256;

  float4_ acc[4][4];
  float4_ z4 = {0.f, 0.f, 0.f, 0.f};
#pragma unroll
  for (int i = 0; i < 4; ++i)
#pragma unroll
    for (int j = 0; j < 4; ++j) acc[i][j] = z4;

  for (int kt = 0; kt < 8; ++kt) {
    const int k0 = kt * 32;
#pragma unroll
    for (int cc = 0; cc < 2; ++cc) {
      int ch = tid + 256 * cc;  // 512 16B-chunks per tile
      load_lds16(Ab + (size_t)(ch >> 2) * 256 + k0 + (ch & 3) * 8, &As[ch * 8]);
      load_lds16(Wb + (size_t)(ch >> 2) * 256 + k0 + (ch & 3) * 8, &Bs[ch * 8]);
    }
    __syncthreads();  // drains global_load_lds (vmcnt) before use
    short8_ af[4], bf[4];
#pragma unroll
    for (int i = 0; i < 4; ++i) {
      af[i] = *(const short8_*)&As[(wr + i * 16 + nl) * 32 + q * 8];
      bf[i] = *(const short8_*)&Bs[(wc + i * 16 + nl) * 32 + q * 8];
    }
#pragma unroll
    for (int i = 0; i < 4; ++i)
#pragma unroll
      for (int j = 0; j < 4; ++j)
        acc[i][j] = __builtin_amdgcn_mfma_f32_16x16x32_bf16(af[i], bf[j], acc[i][j], 0, 0, 0);
    __syncthreads();
  }

  float bv[4];
#pragma unroll
  for (int j = 0; j < 4; ++j) bv[j] = bias[bn * 128 + wc + j * 16 + nl];

  if (bn < 4) {  // r,z columns -> bf16
#pragma unroll
    for (int i = 0; i < 4; ++i)
#pragma unroll
      for (int j = 0; j < 4; ++j) {
        const int gcol = bn * 128 + wc + j * 16 + nl;
#pragma unroll
        for (int r = 0; r < 4; ++r) {
          const size_t grow = bm * 128 + wr + i * 16 + q * 4 + r;
          gxrz[grow * 512 + gcol] = f2bf(acc[i][j][r] + bv[j]);
        }
      }
  } else {  // n columns -> f32
#pragma unroll
    for (int i = 0; i < 4; ++i)
#pragma unroll
      for (int j = 0; j < 4; ++j) {
        const int gcol = bn * 128 + wc + j * 16 + nl;
#pragma unroll
        for (int r = 0; r < 4; ++r) {
          const size_t grow = bm * 128 + wr + i * 16 + q * 4 + r;
          gxn[grow * 256 + (gcol - 512)] = acc[i][j][r] + bv[j];
        }
      }
  }
}

// --------------------------------------------------------------- gru_layer ---
// 4 WGs x 512 threads. WG b owns batch rows [16b,16b+16). Wave w owns h-cols
// [32w,32w+32): 6 acc tiles (r,z,n gates x 2 col-tiles), Whh fragments resident
// in VGPRs (6 tiles x 8 ksteps x short8 = 192 VGPRs/thread).
__global__ __launch_bounds__(512, 2) void gru_layer(
    const unsigned short* __restrict__ gxrz,  // [T*64][512] bf16
    const float* __restrict__ gxn,            // [T*64][256] f32
    const unsigned short* __restrict__ whh,   // [768][256] bf16
    const float* __restrict__ bhhn,           // [256]
    const float* __restrict__ h0,             // [64][256] f32
    unsigned short* __restrict__ outb,        // [T*64][256] bf16 (next layer in) or null
    float* __restrict__ outf,                 // [T*64][256] f32 (final out) or null
    float* __restrict__ hT) {                 // [64][256] f32
  __shared__ alignas(16) unsigned short h_bf[16][264];  // +8 pad: bank-friendly
  __shared__ float h_f[16][256];
  __shared__ alignas(16) unsigned short srz[16 * 512];
  __shared__ alignas(16) float sn[16 * 256];

  const int tid = threadIdx.x;
  const int rb = blockIdx.x * 16;
  const int wave = tid >> 6, lane = tid & 63;
  const int q = lane >> 4, nl = lane & 15;
  const int cb = wave * 32;

  // init h
#pragma unroll
  for (int i = 0; i < 8; ++i) {
    int idx = tid + 512 * i, row = idx >> 8, col = idx & 255;
    float v = h0[(rb + row) * 256 + col];
    h_f[row][col] = v;
    h_bf[row][col] = f2bf(v);
  }

  // Whh fragments -> registers. B-frag: lane&15 = output col n, quad*8+j = k.
  short8_ wf[6][8];
#pragma unroll
  for (int c = 0; c < 2; ++c)
#pragma unroll
    for (int g = 0; g < 3; ++g) {
      const unsigned short* wrow = whh + (size_t)(g * 256 + cb + c * 16 + nl) * 256;
#pragma unroll
      for (int kt = 0; kt < 8; ++kt)
        wf[c * 3 + g][kt] = *(const short8_*)(wrow + kt * 32 + q * 8);
    }
  const float bn_[2] = { bhhn[cb + nl], bhhn[cb + 16 + nl] };

  // prefetch gx(t=0)
  {
    const unsigned short* s0 = gxrz + (size_t)rb * 512;
    const float* s1 = gxn + (size_t)rb * 256;
#pragma unroll
    for (int cc = 0; cc < 2; ++cc) {
      int ch = tid + 512 * cc;
      load_lds16(s0 + ch * 8, &srz[ch * 8]);
      load_lds16(s1 + ch * 4, &sn[ch * 4]);
    }
  }
  __syncthreads();

  for (int t = 0; t < T_; ++t) {
    // ---- MFMA: gh = h . Whh^T (reads h_bf; gx DMA still landing, drained at barrier)
    float4_ acc[6];
    float4_ z4 = {0.f, 0.f, 0.f, 0.f};
#pragma unroll
    for (int u = 0; u < 6; ++u) acc[u] = z4;
#pragma unroll
    for (int kt = 0; kt < 8; ++kt) {
      short8_ af = *(const short8_*)&h_bf[nl][kt * 32 + q * 8];  // A: lane&15 = row m
#pragma unroll
      for (int u = 0; u < 6; ++u)
        acc[u] = __builtin_amdgcn_mfma_f32_16x16x32_bf16(af, wf[u][kt], acc[u], 0, 0, 0);
    }
    __syncthreads();  // all h_bf reads done; gx DMA drained (vmcnt(0) at barrier)

    // ---- gates. C/D layout: col = lane&15, row = 4*quad + reg.
    float hnew[2][4];
#pragma unroll
    for (int c = 0; c < 2; ++c) {
      const int col = cb + c * 16 + nl;
#pragma unroll
      for (int r = 0; r < 4; ++r) {
        const int row = q * 4 + r;
        float xr = bf2f(srz[row * 512 + col]);
        float xz = bf2f(srz[row * 512 + 256 + col]);
        float xn = sn[row * 256 + col];
        float rr = sigmoid_(xr + acc[c * 3 + 0][r]);
        float zz = sigmoid_(xz + acc[c * 3 + 1][r]);
        float nn = tanh_(xn + rr * (acc[c * 3 + 2][r] + bn_[c]));
        float hold = h_f[row][col];
        float hv = nn + zz * (hold - nn);
        hnew[c][r] = hv;
        h_f[row][col] = hv;         // own column slice: no cross-wave hazard
        h_bf[row][col] = f2bf(hv);
      }
    }
    __syncthreads();  // h_new visible to all waves before next MFMA

    // ---- out stores (from regs, drain hidden under next MFMA phase) + prefetch t+1
    const size_t ob = ((size_t)t * 64 + rb) * 256;
    if (outb) {
#pragma unroll
      for (int c = 0; c < 2; ++c)
#pragma unroll
        for (int r = 0; r < 4; ++r)
          outb[ob + (size_t)(q * 4 + r) * 256 + cb + c * 16 + nl] = f2bf(hnew[c][r]);
    }
    if (outf) {
#pragma unroll
      for (int c = 0; c < 2; ++c)
#pragma unroll
        for (int r = 0; r < 4; ++r)
          outf[ob + (size_t)(q * 4 + r) * 256 + cb + c * 16 + nl] = hnew[c][r];
    }
    if (t + 1 < T_) {
      const unsigned short* s0 = gxrz + ((size_t)(t + 1) * 64 + rb) * 512;
      const float* s1 = gxn + ((size_t)(t + 1) * 64 + rb) * 256;
#pragma unroll
      for (int cc = 0; cc < 2; ++cc) {
        int ch = tid + 512 * cc;
        load_lds16(s0 + ch * 8, &srz[ch * 8]);
        load_lds16(s1 + ch * 4, &sn[ch * 4]);
      }
    }
  }

  // final hidden state
#pragma unroll
  for (int i = 0; i < 8; ++i) {
    int idx = tid + 512 * i, row = idx >> 8, col = idx & 255;
    hT[(rb + row) * 256 + col] = h_f[row][col];
  }
}

// ------------------------------------------------------------------ launch ---
extern "C" void kernel_launch(void* const* d_in, const int* in_sizes, int n_in,
                              void* d_out, int out_size, void* d_ws, size_t ws_size,
                              hipStream_t stream) {
  (void)in_sizes; (void)n_in; (void)out_size; (void)ws_size;
  const float* x   = (const float*)d_in[0];
  const float* h0  = (const float*)d_in[1];
  const float* wih = (const float*)d_in[2];
  const float* whh = (const float*)d_in[3];
  const float* bih = (const float*)d_in[4];
  const float* bhh = (const float*)d_in[5];
  float* out = (float*)d_out;
  char* ws = (char*)d_ws;

  // workspace layout (total ~386 MiB)
  unsigned short* gxrz = (unsigned short*)(ws + 0);           // 134,217,728
  float*          gxn  = (float*)(ws + 134217728);            // 134,217,728
  unsigned short* buf0 = (unsigned short*)(ws + 268435456);   //  67,108,864
  unsigned short* buf1 = (unsigned short*)(ws + 335544320);   //  67,108,864
  unsigned short* wihb = (unsigned short*)(ws + 402653184);   //   1,179,648
  unsigned short* whhb = (unsigned short*)(ws + 403832832);   //   1,179,648
  float*         biasf = (float*)(ws + 405012480);            //       9,216
  float*          bhhn = (float*)(ws + 405021696);            //       3,072

  convert_kernel<<<2048, 256, 0, stream>>>(x, wih, whh, bih, bhh,
                                           buf0, wihb, whhb, biasf, bhhn);

  for (int l = 0; l < 3; ++l) {
    const unsigned short* inb = (l & 1) ? buf1 : buf0;
    unsigned short* outbuf    = (l & 1) ? buf0 : buf1;
    gemm_gx<<<dim3(6, 1024), 256, 0, stream>>>(inb, wihb + (size_t)l * G_ * H_,
                                               biasf + l * G_, gxrz, gxn);
    gru_layer<<<4, 512, 0, stream>>>(
        gxrz, gxn, whhb + (size_t)l * G_ * H_, bhhn + l * H_,
        h0 + (size_t)l * B_ * H_,
        (l < 2) ? outbuf : (unsigned short*)nullptr,
        (l == 2) ? out : (float*)nullptr,
        out + (size_t)T_ * B_ * H_ + (size_t)l * B_ * H_);
  }
}